// Round 4
// baseline (1814.397 us; speedup 1.0000x reference)
//
#include <hip/hip_runtime.h>
#include <hip/hip_bf16.h>

// APPNP: z = MLP(x) (bf16 MFMA); then 10x: x_{k+1} = 0.9 * A_hat x_k + 0.1 * z
// CSR built via 256-node buckets to keep scatter writes L2-resident.
// Propagation gathers pre-scaled bf16 rows g = dinv * x_k; alpha-term stored
// as xb0 = bf16(0.1 * z).

#define HIDDEN 256
#define OUTF   64

typedef __attribute__((ext_vector_type(8))) unsigned short ushort8;
typedef __attribute__((ext_vector_type(8))) short short8v;
typedef __attribute__((ext_vector_type(4))) float f32x4;

__device__ inline float b2f(unsigned short u) {
    union { unsigned int i; float f; } c;
    c.i = ((unsigned int)u) << 16;
    return c.f;
}
__device__ inline unsigned short f2b(float f) {
    union { float f; unsigned int i; } c;
    c.f = f;
    unsigned int x = c.i;
    unsigned int r = (x + 0x7fff + ((x >> 16) & 1)) >> 16;  // RNE
    return (unsigned short)r;
}

// ---------- int64/int32 edge-index hedge ----------
__device__ inline bool detect_i64(const int* __restrict__ p) {
    int acc = 0;
#pragma unroll
    for (int i = 0; i < 16; ++i) acc |= p[2 * i + 1];
    return acc == 0;
}
__device__ inline int load_idx(const void* eiv, long long flat, bool is64) {
    if (is64) return (int)((const long long*)eiv)[flat];
    return ((const int*)eiv)[flat];
}

// ---------- P0: bucket counts (bucket = tgt >> 8) ----------
__global__ __launch_bounds__(256) void bucket_count_kernel(const void* __restrict__ eiv,
                                                           long long E, int* __restrict__ bcnt,
                                                           int n, int nb) {
    __shared__ int hist[512];
    bool is64 = detect_i64((const int*)eiv);
    int t = threadIdx.x;
    for (int i = t; i < nb; i += 256) hist[i] = 0;
    __syncthreads();
    long long stride = (long long)gridDim.x * 256;
    for (long long e = (long long)blockIdx.x * 256 + t; e < E; e += stride) {
        int c = load_idx(eiv, E + e, is64);
        if ((unsigned)c < (unsigned)n) atomicAdd(&hist[c >> 8], 1);
    }
    __syncthreads();
    for (int i = t; i < nb; i += 256)
        if (hist[i]) atomicAdd(&bcnt[i], hist[i]);
}

// ---------- bucket scan: bcnt -> bofs (exclusive), bcur copy ----------
__global__ __launch_bounds__(512) void bucket_scan_kernel(const int* __restrict__ bcnt,
                                                          int* __restrict__ bofs,
                                                          int* __restrict__ bcur, int nb) {
    __shared__ int s[512];
    int t = threadIdx.x;
    int v = (t < nb) ? bcnt[t] : 0;
    s[t] = v;
    __syncthreads();
    for (int o = 1; o < 512; o <<= 1) {
        int tv = (t >= o) ? s[t - o] : 0;
        __syncthreads();
        s[t] += tv;
        __syncthreads();
    }
    if (t < nb) {
        bofs[t] = s[t] - v;
        bcur[t] = s[t] - v;
    }
    if (t == 511) bofs[nb] = s[511];
}

// ---------- P1: scatter (tgt,src) pairs into bucket regions ----------
__global__ __launch_bounds__(256) void scatter_pairs_kernel(const void* __restrict__ eiv,
                                                            long long E, int* __restrict__ bcur,
                                                            int2* __restrict__ pairs, int n) {
    bool is64 = detect_i64((const int*)eiv);
    long long stride = (long long)gridDim.x * 256;
    for (long long e = (long long)blockIdx.x * 256 + threadIdx.x; e < E; e += stride) {
        int r = load_idx(eiv, e, is64);
        int c = load_idx(eiv, E + e, is64);
        if ((unsigned)c >= (unsigned)n || (unsigned)r >= (unsigned)n) continue;
        int pos = atomicAdd(&bcur[c >> 8], 1);
        pairs[pos] = make_int2(c, r);
    }
}

// ---------- P2: per-bucket CSR build + dinv ----------
__global__ __launch_bounds__(256) void csr_bucket_kernel(const int2* __restrict__ pairs,
                                                         const int* __restrict__ bofs,
                                                         int* __restrict__ ofs,
                                                         float* __restrict__ dinv,
                                                         int* __restrict__ csr_src,
                                                         int n, int nb) {
    __shared__ int hist[256];
    __shared__ int scn[256];
    int b = blockIdx.x;
    int t = threadIdx.x;
    int node0 = b << 8;
    int cnt = min(256, n - node0);

    hist[t] = 0;
    __syncthreads();
    int beg = bofs[b], end = bofs[b + 1];
    for (int e = beg + t; e < end; e += 256) atomicAdd(&hist[pairs[e].x & 255], 1);
    __syncthreads();
    int v = hist[t];
    scn[t] = v;
    __syncthreads();
    for (int o = 1; o < 256; o <<= 1) {
        int tv = (t >= o) ? scn[t - o] : 0;
        __syncthreads();
        scn[t] += tv;
        __syncthreads();
    }
    int excl = scn[t] - v;
    if (t < cnt) {
        ofs[node0 + t] = beg + excl;
        dinv[node0 + t] = rsqrtf((float)(v + 1));
    }
    if (b == nb - 1 && t == 0) ofs[n] = end;
    __syncthreads();
    hist[t] = beg + excl;  // reuse as cursor
    __syncthreads();
    for (int e = beg + t; e < end; e += 256) {
        int2 p = pairs[e];
        int pos = atomicAdd(&hist[p.x & 255], 1);
        csr_src[pos] = p.y;
    }
}

// ---------- fused MFMA MLP: z = relu(x@w1.T+b1)@w2.T+b2 ----------
// Epilogue writes xb0 = bf16(0.1*z) and g0 = bf16(dinv*z).
#define MLP_BM 64
__global__ __launch_bounds__(256) void mlp_mfma_kernel(const float* __restrict__ x,
                                                       const float* __restrict__ w1,
                                                       const float* __restrict__ b1,
                                                       const float* __restrict__ w2,
                                                       const float* __restrict__ b2,
                                                       const float* __restrict__ dinv,
                                                       unsigned short* __restrict__ xb0,
                                                       unsigned short* __restrict__ g0, int n) {
    __shared__ __align__(16) unsigned short regA[16384];      // 32 KB
    __shared__ __align__(16) unsigned short h_lds[64 * 264];  // 33 KB

    const int t = threadIdx.x;
    const int w = t >> 6;
    const int l = t & 63;
    const int c = l & 15, g = l >> 4;
    const int node0 = blockIdx.x * MLP_BM;

    f32x4 acc[4][4];
#pragma unroll
    for (int a = 0; a < 4; ++a)
#pragma unroll
        for (int b = 0; b < 4; ++b) acc[a][b] = (f32x4)0.f;

    for (int ks = 0; ks < 8; ++ks) {
        const int k0 = ks * 32;
        {
            int kg = t & 3, m = t >> 2;
            int node = node0 + m;
            float4 A = make_float4(0.f, 0.f, 0.f, 0.f), B = A;
            if (node < n) {
                const float4* xp = (const float4*)(x + (size_t)node * HIDDEN + k0 + kg * 8);
                A = xp[0];
                B = xp[1];
            }
            short8v o;
            o[0] = (short)f2b(A.x); o[1] = (short)f2b(A.y);
            o[2] = (short)f2b(A.z); o[3] = (short)f2b(A.w);
            o[4] = (short)f2b(B.x); o[5] = (short)f2b(B.y);
            o[6] = (short)f2b(B.z); o[7] = (short)f2b(B.w);
            *(short8v*)&regA[8192 + (((m >> 4) * 64 + kg * 16 + (m & 15)) << 3)] = o;
        }
#pragma unroll
        for (int p = 0; p < 4; ++p) {
            int kg = t & 3, f = p * 64 + (t >> 2);
            const float4* wp = (const float4*)(w1 + (size_t)f * HIDDEN + k0 + kg * 8);
            float4 A = wp[0], B = wp[1];
            short8v o;
            o[0] = (short)f2b(A.x); o[1] = (short)f2b(A.y);
            o[2] = (short)f2b(A.z); o[3] = (short)f2b(A.w);
            o[4] = (short)f2b(B.x); o[5] = (short)f2b(B.y);
            o[6] = (short)f2b(B.z); o[7] = (short)f2b(B.w);
            *(short8v*)&regA[(((f >> 4) * 64 + kg * 16 + (f & 15)) << 3)] = o;
        }
        __syncthreads();
        short8v af[4], bf[4];
#pragma unroll
        for (int mt = 0; mt < 4; ++mt)
            af[mt] = *(const short8v*)&regA[8192 + ((mt * 64 + l) << 3)];
#pragma unroll
        for (int nt = 0; nt < 4; ++nt)
            bf[nt] = *(const short8v*)&regA[(((w * 4 + nt) * 64 + l) << 3)];
#pragma unroll
        for (int mt = 0; mt < 4; ++mt)
#pragma unroll
            for (int nt = 0; nt < 4; ++nt)
                acc[mt][nt] =
                    __builtin_amdgcn_mfma_f32_16x16x32_bf16(af[mt], bf[nt], acc[mt][nt], 0, 0, 0);
        __syncthreads();
    }

#pragma unroll
    for (int nt = 0; nt < 4; ++nt) {
        int col = w * 64 + nt * 16 + c;
        float b1v = b1[col];
#pragma unroll
        for (int mt = 0; mt < 4; ++mt)
#pragma unroll
            for (int r = 0; r < 4; ++r) {
                int row = mt * 16 + g * 4 + r;
                float hv = fmaxf(acc[mt][nt][r] + b1v, 0.f);
                h_lds[row * 264 + col] = f2b(hv);
            }
    }
#pragma unroll
    for (int p = 0; p < 8; ++p) {
        int j = p * 8 + (t >> 5);
        int kslot = t & 31;
        const float4* wp = (const float4*)(w2 + (size_t)j * HIDDEN + kslot * 8);
        float4 A = wp[0], B = wp[1];
        short8v o;
        o[0] = (short)f2b(A.x); o[1] = (short)f2b(A.y);
        o[2] = (short)f2b(A.z); o[3] = (short)f2b(A.w);
        o[4] = (short)f2b(B.x); o[5] = (short)f2b(B.y);
        o[6] = (short)f2b(B.z); o[7] = (short)f2b(B.w);
        *(short8v*)&regA[(((j >> 4) * 512 + (kslot >> 2) * 64 + (kslot & 3) * 16 + (j & 15)) << 3)] = o;
    }
    __syncthreads();

    f32x4 acc2[4];
#pragma unroll
    for (int nt = 0; nt < 4; ++nt) acc2[nt] = (f32x4)0.f;
#pragma unroll
    for (int ks = 0; ks < 8; ++ks) {
        short8v a2 = *(const short8v*)&h_lds[(w * 16 + c) * 264 + ks * 32 + g * 8];
#pragma unroll
        for (int nt = 0; nt < 4; ++nt) {
            short8v b2v = *(const short8v*)&regA[((nt * 512 + ks * 64 + l) << 3)];
            acc2[nt] = __builtin_amdgcn_mfma_f32_16x16x32_bf16(a2, b2v, acc2[nt], 0, 0, 0);
        }
    }
#pragma unroll
    for (int nt = 0; nt < 4; ++nt) {
        int col = nt * 16 + c;
        float bb = b2[col];
#pragma unroll
        for (int r = 0; r < 4; ++r) {
            int node = node0 + w * 16 + g * 4 + r;
            if (node < n) {
                float zv = acc2[nt][r] + bb;
                float di = dinv[node];
                xb0[(size_t)node * OUTF + col] = f2b(0.1f * zv);
                g0[(size_t)node * OUTF + col] = f2b(di * zv);
            }
        }
    }
}

// ---------- propagation step ----------
template <int LAST>
__global__ __launch_bounds__(256) void prop_kernel(const unsigned short* __restrict__ gk,
                                                   const unsigned short* __restrict__ xb0,
                                                   unsigned short* __restrict__ gn,
                                                   float* __restrict__ out,
                                                   const int* __restrict__ ofs,
                                                   const int* __restrict__ csr_src,
                                                   const float* __restrict__ dinv, int n) {
    int gid = blockIdx.x * 256 + threadIdx.x;
    int node = gid >> 3;
    int part = gid & 7;
    if (node >= n) return;

    int beg = ofs[node];
    int end = ofs[node + 1];
    float di = dinv[node];

    float acc[8];
#pragma unroll
    for (int j = 0; j < 8; ++j) acc[j] = 0.f;

    const size_t poff = (size_t)part * 8;
    int e = beg;
    for (; e + 1 < end; e += 2) {
        int s0 = csr_src[e];
        int s1 = csr_src[e + 1];
        ushort8 a = *(const ushort8*)(gk + (size_t)s0 * OUTF + poff);
        ushort8 b = *(const ushort8*)(gk + (size_t)s1 * OUTF + poff);
#pragma unroll
        for (int j = 0; j < 8; ++j) acc[j] += b2f(a[j]);
#pragma unroll
        for (int j = 0; j < 8; ++j) acc[j] += b2f(b[j]);
    }
    if (e < end) {
        int s0 = csr_src[e];
        ushort8 a = *(const ushort8*)(gk + (size_t)s0 * OUTF + poff);
#pragma unroll
        for (int j = 0; j < 8; ++j) acc[j] += b2f(a[j]);
    }
    {
        ushort8 a = *(const ushort8*)(gk + (size_t)node * OUTF + poff);
#pragma unroll
        for (int j = 0; j < 8; ++j) acc[j] += b2f(a[j]);
    }

    ushort8 xv = *(const ushort8*)(xb0 + (size_t)node * OUTF + poff);
    float res[8];
#pragma unroll
    for (int j = 0; j < 8; ++j) res[j] = 0.9f * di * acc[j] + b2f(xv[j]);

    if (LAST) {
        float4* o4 = (float4*)(out + (size_t)node * OUTF + poff);
        o4[0] = make_float4(res[0], res[1], res[2], res[3]);
        o4[1] = make_float4(res[4], res[5], res[6], res[7]);
    } else {
        ushort8 o;
#pragma unroll
        for (int j = 0; j < 8; ++j) o[j] = f2b(di * res[j]);
        *(ushort8*)(gn + (size_t)node * OUTF + poff) = o;
    }
}

extern "C" void kernel_launch(void* const* d_in, const int* in_sizes, int n_in,
                              void* d_out, int out_size, void* d_ws, size_t ws_size,
                              hipStream_t stream) {
    const float* x = (const float*)d_in[0];
    const void* ei = d_in[1];
    const float* w1 = (const float*)d_in[2];
    const float* b1 = (const float*)d_in[3];
    const float* w2 = (const float*)d_in[4];
    const float* b2 = (const float*)d_in[5];
    float* out = (float*)d_out;

    int n = in_sizes[0] / HIDDEN;              // 100000
    long long E = (long long)in_sizes[1] / 2;  // 3200000
    int nb = (n + 255) >> 8;                   // 391 buckets

    char* ws = (char*)d_ws;
    size_t off = 0;
    auto alloc = [&](size_t bytes) {
        void* p = ws + off;
        off += (bytes + 511) & ~(size_t)511;
        return p;
    };
    unsigned short* xb0 = (unsigned short*)alloc((size_t)n * OUTF * 2);  // 12.8 MB
    // gA/gB union with pairs (pairs dead before mlp writes g0=gA)
    size_t gmark = off;
    unsigned short* gA = (unsigned short*)alloc((size_t)n * OUTF * 2);   // 12.8 MB
    unsigned short* gB = (unsigned short*)alloc((size_t)n * OUTF * 2);   // 12.8 MB
    int2* pairs = (int2*)(ws + gmark);                                   // aliases gA/gB
    float* dinv = (float*)alloc((size_t)n * 4);
    int* ofs = (int*)alloc((size_t)(n + 1) * 4);
    int* csr_src = (int*)alloc((size_t)E * 4);                           // 12.8 MB
    int* bcnt = (int*)alloc(512 * 4);
    int* bofs = (int*)alloc(513 * 4);
    int* bcur = (int*)alloc(512 * 4);

    hipMemsetAsync(bcnt, 0, 512 * 4, stream);

    bucket_count_kernel<<<1024, 256, 0, stream>>>(ei, E, bcnt, n, nb);
    bucket_scan_kernel<<<1, 512, 0, stream>>>(bcnt, bofs, bcur, nb);
    scatter_pairs_kernel<<<1024, 256, 0, stream>>>(ei, E, bcur, pairs, n);
    csr_bucket_kernel<<<nb, 256, 0, stream>>>(pairs, bofs, ofs, dinv, csr_src, n, nb);

    mlp_mfma_kernel<<<(n + MLP_BM - 1) / MLP_BM, 256, 0, stream>>>(x, w1, b1, w2, b2, dinv,
                                                                   xb0, gA, n);

    int prop_blocks = (int)(((size_t)n * 8 + 255) / 256);
    for (int k = 0; k < 10; ++k) {
        const unsigned short* gin = (k & 1) ? gB : gA;
        unsigned short* gout = (k & 1) ? gA : gB;
        if (k == 9) {
            prop_kernel<1><<<prop_blocks, 256, 0, stream>>>(gin, xb0, nullptr, out, ofs,
                                                            csr_src, dinv, n);
        } else {
            prop_kernel<0><<<prop_blocks, 256, 0, stream>>>(gin, xb0, gout, nullptr, ofs,
                                                            csr_src, dinv, n);
        }
    }
}

// Round 5
// 725.723 us; speedup vs baseline: 2.5001x; 2.5001x over previous
//
#include <hip/hip_runtime.h>
#include <hip/hip_bf16.h>

// APPNP: z = MLP(x) (bf16 MFMA); then 10x: x_{k+1} = 0.9 * A_hat x_k + 0.1 * z
// CSR built via contention-free two-pass bucket partition (bucket = tgt>>8),
// then per-bucket node-level CSR in L2-resident 32KB windows.
// Propagation gathers pre-scaled bf16 rows g = dinv * x_k; alpha-term stored
// as xb0 = bf16(0.1 * z).

#define HIDDEN 256
#define OUTF   64
#define NB_BLK 256   // partition blocks (fixed; per-block chunk of edges)

typedef __attribute__((ext_vector_type(8))) unsigned short ushort8;
typedef __attribute__((ext_vector_type(8))) short short8v;
typedef __attribute__((ext_vector_type(4))) float f32x4;

__device__ inline float b2f(unsigned short u) {
    union { unsigned int i; float f; } c;
    c.i = ((unsigned int)u) << 16;
    return c.f;
}
__device__ inline unsigned short f2b(float f) {
    union { float f; unsigned int i; } c;
    c.f = f;
    unsigned int x = c.i;
    unsigned int r = (x + 0x7fff + ((x >> 16) & 1)) >> 16;  // RNE
    return (unsigned short)r;
}

// ---------- int64/int32 edge-index hedge ----------
__device__ inline bool detect_i64(const int* __restrict__ p) {
    int acc = 0;
#pragma unroll
    for (int i = 0; i < 16; ++i) acc |= p[2 * i + 1];
    return acc == 0;
}
__device__ inline int load_idx(const void* eiv, long long flat, bool is64) {
    if (is64) return (int)((const long long*)eiv)[flat];
    return ((const int*)eiv)[flat];
}

// ---------- P0: per-block bucket histogram ----------
__global__ __launch_bounds__(256) void part_hist_kernel(const void* __restrict__ eiv,
                                                        long long E, int* __restrict__ bh,
                                                        int n, int nb) {
    __shared__ int hist[512];
    bool is64 = detect_i64((const int*)eiv);
    int t = threadIdx.x, b = blockIdx.x;
    for (int i = t; i < 512; i += 256) hist[i] = 0;
    __syncthreads();
    long long chunk = (E + NB_BLK - 1) / NB_BLK;
    long long beg = (long long)b * chunk, end = min(E, beg + chunk);
    for (long long e = beg + t; e < end; e += 256) {
        int c = load_idx(eiv, E + e, is64);
        if ((unsigned)c < (unsigned)n) atomicAdd(&hist[c >> 8], 1);
    }
    __syncthreads();
    for (int i = t; i < nb; i += 256) bh[i * NB_BLK + b] = hist[i];
}

// ---------- P1a: per-bucket scan over blocks -> pre, btot ----------
__global__ __launch_bounds__(256) void part_colscan_kernel(const int* __restrict__ bh,
                                                           int* __restrict__ pre,
                                                           int* __restrict__ btot) {
    __shared__ int s[NB_BLK];
    int g = blockIdx.x, t = threadIdx.x;
    int v = bh[g * NB_BLK + t];
    s[t] = v;
    __syncthreads();
    for (int o = 1; o < NB_BLK; o <<= 1) {
        int tv = (t >= o) ? s[t - o] : 0;
        __syncthreads();
        s[t] += tv;
        __syncthreads();
    }
    pre[g * NB_BLK + t] = s[t] - v;
    if (t == NB_BLK - 1) btot[g] = s[t];
}

// ---------- P1b: scan over buckets -> bofs ----------
__global__ __launch_bounds__(512) void part_bscan_kernel(const int* __restrict__ btot,
                                                         int* __restrict__ bofs, int nb) {
    __shared__ int s[512];
    int t = threadIdx.x;
    int v = (t < nb) ? btot[t] : 0;
    s[t] = v;
    __syncthreads();
    for (int o = 1; o < 512; o <<= 1) {
        int tv = (t >= o) ? s[t - o] : 0;
        __syncthreads();
        s[t] += tv;
        __syncthreads();
    }
    if (t < nb) bofs[t] = s[t] - v;
    if (t == 511) bofs[nb] = s[511];
}

// ---------- P2: stable scatter into bucket regions (LDS cursors only) ----------
__global__ __launch_bounds__(256) void part_scatter_kernel(const void* __restrict__ eiv,
                                                           long long E,
                                                           const int* __restrict__ bofs,
                                                           const int* __restrict__ pre,
                                                           int2* __restrict__ pairs,
                                                           int n, int nb) {
    __shared__ int cur[512];
    bool is64 = detect_i64((const int*)eiv);
    int t = threadIdx.x, b = blockIdx.x;
    for (int i = t; i < nb; i += 256) cur[i] = bofs[i] + pre[i * NB_BLK + b];
    __syncthreads();
    long long chunk = (E + NB_BLK - 1) / NB_BLK;
    long long beg = (long long)b * chunk, end = min(E, beg + chunk);
    for (long long e = beg + t; e < end; e += 256) {
        int r = load_idx(eiv, e, is64);
        int c = load_idx(eiv, E + e, is64);
        if ((unsigned)c >= (unsigned)n || (unsigned)r >= (unsigned)n) continue;
        int pos = atomicAdd(&cur[c >> 8], 1);
        pairs[pos] = make_int2(c, r);
    }
}

// ---------- P3: per-bucket CSR build + dinv ----------
__global__ __launch_bounds__(256) void csr_bucket_kernel(const int2* __restrict__ pairs,
                                                         const int* __restrict__ bofs,
                                                         int* __restrict__ ofs,
                                                         float* __restrict__ dinv,
                                                         int* __restrict__ csr_src,
                                                         int n, int nb) {
    __shared__ int hist[256];
    __shared__ int scn[256];
    int b = blockIdx.x;
    int t = threadIdx.x;
    int node0 = b << 8;
    int cnt = min(256, n - node0);

    hist[t] = 0;
    __syncthreads();
    int beg = bofs[b], end = bofs[b + 1];
    for (int e = beg + t; e < end; e += 256) atomicAdd(&hist[pairs[e].x & 255], 1);
    __syncthreads();
    int v = hist[t];
    scn[t] = v;
    __syncthreads();
    for (int o = 1; o < 256; o <<= 1) {
        int tv = (t >= o) ? scn[t - o] : 0;
        __syncthreads();
        scn[t] += tv;
        __syncthreads();
    }
    int excl = scn[t] - v;
    if (t < cnt) {
        ofs[node0 + t] = beg + excl;
        dinv[node0 + t] = rsqrtf((float)(v + 1));
    }
    if (b == nb - 1 && t == 0) ofs[n] = end;
    __syncthreads();
    hist[t] = beg + excl;  // reuse as cursor
    __syncthreads();
    for (int e = beg + t; e < end; e += 256) {
        int2 p = pairs[e];
        int pos = atomicAdd(&hist[p.x & 255], 1);
        csr_src[pos] = p.y;
    }
}

// ---------- fused MFMA MLP: z = relu(x@w1.T+b1)@w2.T+b2 ----------
// Epilogue writes xb0 = bf16(0.1*z) and g0 = bf16(dinv*z).
#define MLP_BM 64
__global__ __launch_bounds__(256) void mlp_mfma_kernel(const float* __restrict__ x,
                                                       const float* __restrict__ w1,
                                                       const float* __restrict__ b1,
                                                       const float* __restrict__ w2,
                                                       const float* __restrict__ b2,
                                                       const float* __restrict__ dinv,
                                                       unsigned short* __restrict__ xb0,
                                                       unsigned short* __restrict__ g0, int n) {
    __shared__ __align__(16) unsigned short regA[16384];      // 32 KB
    __shared__ __align__(16) unsigned short h_lds[64 * 264];  // 33 KB

    const int t = threadIdx.x;
    const int w = t >> 6;
    const int l = t & 63;
    const int c = l & 15, g = l >> 4;
    const int node0 = blockIdx.x * MLP_BM;

    f32x4 acc[4][4];
#pragma unroll
    for (int a = 0; a < 4; ++a)
#pragma unroll
        for (int b = 0; b < 4; ++b) acc[a][b] = (f32x4)0.f;

    for (int ks = 0; ks < 8; ++ks) {
        const int k0 = ks * 32;
        {
            int kg = t & 3, m = t >> 2;
            int node = node0 + m;
            float4 A = make_float4(0.f, 0.f, 0.f, 0.f), B = A;
            if (node < n) {
                const float4* xp = (const float4*)(x + (size_t)node * HIDDEN + k0 + kg * 8);
                A = xp[0];
                B = xp[1];
            }
            short8v o;
            o[0] = (short)f2b(A.x); o[1] = (short)f2b(A.y);
            o[2] = (short)f2b(A.z); o[3] = (short)f2b(A.w);
            o[4] = (short)f2b(B.x); o[5] = (short)f2b(B.y);
            o[6] = (short)f2b(B.z); o[7] = (short)f2b(B.w);
            *(short8v*)&regA[8192 + (((m >> 4) * 64 + kg * 16 + (m & 15)) << 3)] = o;
        }
#pragma unroll
        for (int p = 0; p < 4; ++p) {
            int kg = t & 3, f = p * 64 + (t >> 2);
            const float4* wp = (const float4*)(w1 + (size_t)f * HIDDEN + k0 + kg * 8);
            float4 A = wp[0], B = wp[1];
            short8v o;
            o[0] = (short)f2b(A.x); o[1] = (short)f2b(A.y);
            o[2] = (short)f2b(A.z); o[3] = (short)f2b(A.w);
            o[4] = (short)f2b(B.x); o[5] = (short)f2b(B.y);
            o[6] = (short)f2b(B.z); o[7] = (short)f2b(B.w);
            *(short8v*)&regA[(((f >> 4) * 64 + kg * 16 + (f & 15)) << 3)] = o;
        }
        __syncthreads();
        short8v af[4], bf[4];
#pragma unroll
        for (int mt = 0; mt < 4; ++mt)
            af[mt] = *(const short8v*)&regA[8192 + ((mt * 64 + l) << 3)];
#pragma unroll
        for (int nt = 0; nt < 4; ++nt)
            bf[nt] = *(const short8v*)&regA[(((w * 4 + nt) * 64 + l) << 3)];
#pragma unroll
        for (int mt = 0; mt < 4; ++mt)
#pragma unroll
            for (int nt = 0; nt < 4; ++nt)
                acc[mt][nt] =
                    __builtin_amdgcn_mfma_f32_16x16x32_bf16(af[mt], bf[nt], acc[mt][nt], 0, 0, 0);
        __syncthreads();
    }

#pragma unroll
    for (int nt = 0; nt < 4; ++nt) {
        int col = w * 64 + nt * 16 + c;
        float b1v = b1[col];
#pragma unroll
        for (int mt = 0; mt < 4; ++mt)
#pragma unroll
            for (int r = 0; r < 4; ++r) {
                int row = mt * 16 + g * 4 + r;
                float hv = fmaxf(acc[mt][nt][r] + b1v, 0.f);
                h_lds[row * 264 + col] = f2b(hv);
            }
    }
#pragma unroll
    for (int p = 0; p < 8; ++p) {
        int j = p * 8 + (t >> 5);
        int kslot = t & 31;
        const float4* wp = (const float4*)(w2 + (size_t)j * HIDDEN + kslot * 8);
        float4 A = wp[0], B = wp[1];
        short8v o;
        o[0] = (short)f2b(A.x); o[1] = (short)f2b(A.y);
        o[2] = (short)f2b(A.z); o[3] = (short)f2b(A.w);
        o[4] = (short)f2b(B.x); o[5] = (short)f2b(B.y);
        o[6] = (short)f2b(B.z); o[7] = (short)f2b(B.w);
        *(short8v*)&regA[(((j >> 4) * 512 + (kslot >> 2) * 64 + (kslot & 3) * 16 + (j & 15)) << 3)] = o;
    }
    __syncthreads();

    f32x4 acc2[4];
#pragma unroll
    for (int nt = 0; nt < 4; ++nt) acc2[nt] = (f32x4)0.f;
#pragma unroll
    for (int ks = 0; ks < 8; ++ks) {
        short8v a2 = *(const short8v*)&h_lds[(w * 16 + c) * 264 + ks * 32 + g * 8];
#pragma unroll
        for (int nt = 0; nt < 4; ++nt) {
            short8v b2v = *(const short8v*)&regA[((nt * 512 + ks * 64 + l) << 3)];
            acc2[nt] = __builtin_amdgcn_mfma_f32_16x16x32_bf16(a2, b2v, acc2[nt], 0, 0, 0);
        }
    }
#pragma unroll
    for (int nt = 0; nt < 4; ++nt) {
        int col = nt * 16 + c;
        float bb = b2[col];
#pragma unroll
        for (int r = 0; r < 4; ++r) {
            int node = node0 + w * 16 + g * 4 + r;
            if (node < n) {
                float zv = acc2[nt][r] + bb;
                float di = dinv[node];
                xb0[(size_t)node * OUTF + col] = f2b(0.1f * zv);
                g0[(size_t)node * OUTF + col] = f2b(di * zv);
            }
        }
    }
}

// ---------- propagation step ----------
template <int LAST>
__global__ __launch_bounds__(256) void prop_kernel(const unsigned short* __restrict__ gk,
                                                   const unsigned short* __restrict__ xb0,
                                                   unsigned short* __restrict__ gn,
                                                   float* __restrict__ out,
                                                   const int* __restrict__ ofs,
                                                   const int* __restrict__ csr_src,
                                                   const float* __restrict__ dinv, int n) {
    int gid = blockIdx.x * 256 + threadIdx.x;
    int node = gid >> 3;
    int part = gid & 7;
    if (node >= n) return;

    int beg = ofs[node];
    int end = ofs[node + 1];
    float di = dinv[node];

    float acc[8];
#pragma unroll
    for (int j = 0; j < 8; ++j) acc[j] = 0.f;

    const size_t poff = (size_t)part * 8;
    int e = beg;
    for (; e + 1 < end; e += 2) {
        int s0 = csr_src[e];
        int s1 = csr_src[e + 1];
        ushort8 a = *(const ushort8*)(gk + (size_t)s0 * OUTF + poff);
        ushort8 b = *(const ushort8*)(gk + (size_t)s1 * OUTF + poff);
#pragma unroll
        for (int j = 0; j < 8; ++j) acc[j] += b2f(a[j]);
#pragma unroll
        for (int j = 0; j < 8; ++j) acc[j] += b2f(b[j]);
    }
    if (e < end) {
        int s0 = csr_src[e];
        ushort8 a = *(const ushort8*)(gk + (size_t)s0 * OUTF + poff);
#pragma unroll
        for (int j = 0; j < 8; ++j) acc[j] += b2f(a[j]);
    }
    {
        ushort8 a = *(const ushort8*)(gk + (size_t)node * OUTF + poff);
#pragma unroll
        for (int j = 0; j < 8; ++j) acc[j] += b2f(a[j]);
    }

    ushort8 xv = *(const ushort8*)(xb0 + (size_t)node * OUTF + poff);
    float res[8];
#pragma unroll
    for (int j = 0; j < 8; ++j) res[j] = 0.9f * di * acc[j] + b2f(xv[j]);

    if (LAST) {
        float4* o4 = (float4*)(out + (size_t)node * OUTF + poff);
        o4[0] = make_float4(res[0], res[1], res[2], res[3]);
        o4[1] = make_float4(res[4], res[5], res[6], res[7]);
    } else {
        ushort8 o;
#pragma unroll
        for (int j = 0; j < 8; ++j) o[j] = f2b(di * res[j]);
        *(ushort8*)(gn + (size_t)node * OUTF + poff) = o;
    }
}

extern "C" void kernel_launch(void* const* d_in, const int* in_sizes, int n_in,
                              void* d_out, int out_size, void* d_ws, size_t ws_size,
                              hipStream_t stream) {
    const float* x = (const float*)d_in[0];
    const void* ei = d_in[1];
    const float* w1 = (const float*)d_in[2];
    const float* b1 = (const float*)d_in[3];
    const float* w2 = (const float*)d_in[4];
    const float* b2 = (const float*)d_in[5];
    float* out = (float*)d_out;

    int n = in_sizes[0] / HIDDEN;              // 100000
    long long E = (long long)in_sizes[1] / 2;  // 3200000
    int nb = (n + 255) >> 8;                   // 391 buckets

    char* ws = (char*)d_ws;
    size_t off = 0;
    auto alloc = [&](size_t bytes) {
        void* p = ws + off;
        off += (bytes + 511) & ~(size_t)511;
        return p;
    };
    unsigned short* xb0 = (unsigned short*)alloc((size_t)n * OUTF * 2);  // 12.8 MB
    // gA/gB union with pairs (pairs dead before mlp writes g0=gA)
    size_t gmark = off;
    unsigned short* gA = (unsigned short*)alloc((size_t)n * OUTF * 2);   // 12.8 MB
    unsigned short* gB = (unsigned short*)alloc((size_t)n * OUTF * 2);   // 12.8 MB
    int2* pairs = (int2*)(ws + gmark);                                   // aliases gA/gB
    float* dinv = (float*)alloc((size_t)n * 4);
    int* ofs = (int*)alloc((size_t)(n + 1) * 4);
    int* csr_src = (int*)alloc((size_t)E * 4);                           // 12.8 MB
    int* bh = (int*)alloc((size_t)512 * NB_BLK * 4);                     // 512 KB
    int* pre = (int*)alloc((size_t)512 * NB_BLK * 4);                    // 512 KB
    int* btot = (int*)alloc(512 * 4);
    int* bofs = (int*)alloc(513 * 4);

    part_hist_kernel<<<NB_BLK, 256, 0, stream>>>(ei, E, bh, n, nb);
    part_colscan_kernel<<<nb, NB_BLK, 0, stream>>>(bh, pre, btot);
    part_bscan_kernel<<<1, 512, 0, stream>>>(btot, bofs, nb);
    part_scatter_kernel<<<NB_BLK, 256, 0, stream>>>(ei, E, bofs, pre, pairs, n, nb);
    csr_bucket_kernel<<<nb, 256, 0, stream>>>(pairs, bofs, ofs, dinv, csr_src, n, nb);

    mlp_mfma_kernel<<<(n + MLP_BM - 1) / MLP_BM, 256, 0, stream>>>(x, w1, b1, w2, b2, dinv,
                                                                   xb0, gA, n);

    int prop_blocks = (int)(((size_t)n * 8 + 255) / 256);
    for (int k = 0; k < 10; ++k) {
        const unsigned short* gin = (k & 1) ? gB : gA;
        unsigned short* gout = (k & 1) ? gA : gB;
        if (k == 9) {
            prop_kernel<1><<<prop_blocks, 256, 0, stream>>>(gin, xb0, nullptr, out, ofs,
                                                            csr_src, dinv, n);
        } else {
            prop_kernel<0><<<prop_blocks, 256, 0, stream>>>(gin, xb0, gout, nullptr, ofs,
                                                            csr_src, dinv, n);
        }
    }
}